// Round 6
// baseline (242.985 us; speedup 1.0000x reference)
//
#include <hip/hip_runtime.h>

typedef float f4 __attribute__((ext_vector_type(4)));
typedef __attribute__((ext_vector_type(8))) short bf16x8;
typedef __attribute__((ext_vector_type(4))) float f32x4;
typedef __attribute__((ext_vector_type(2))) int i32x2;

#define T_SEQ 2048
#define NFEAT 512
#define NHEAD 8
#define DK    64
#define BATCH 4

using gptr_t = const __attribute__((address_space(1))) void*;
using lptr_t = __attribute__((address_space(3))) void*;

#define LOG2E_8 0.18033688011f   // 0.125 * log2(e)

static __device__ __forceinline__ short f2bf(float f) {
    unsigned u = __builtin_bit_cast(unsigned, f);
    u += 0x7fff + ((u >> 16) & 1);          // round-to-nearest-even
    return (short)(u >> 16);
}
static __device__ __forceinline__ float b2f(short s) {
    unsigned u = ((unsigned)(unsigned short)s) << 16;
    return __builtin_bit_cast(float, u);
}
// pack two floats -> two bf16 (cheap round) in one int
static __device__ __forceinline__ int pkbf(float a, float b) {
    unsigned ua = __builtin_bit_cast(unsigned, a) + 0x8000u;
    unsigned ub = __builtin_bit_cast(unsigned, b) + 0x8000u;
    return (int)((ua >> 16) | (ub & 0xFFFF0000u));
}

// ---------------- fused fp32->bf16 conversion + weight/bias packing -------------
__global__ __launch_bounds__(256) void cvt_kernel(
    const float* __restrict__ x, const float* __restrict__ pos,
    const float* __restrict__ Wq, const float* __restrict__ Wk, const float* __restrict__ Wv,
    const float* __restrict__ Wpos, const float* __restrict__ Wout,
    const float* __restrict__ bq, const float* __restrict__ bk, const float* __restrict__ bv,
    short* __restrict__ xb, short* __restrict__ posb, short* __restrict__ wqkv,
    short* __restrict__ wpb, short* __restrict__ wob, float* __restrict__ bqkv)
{
    const int blk = blockIdx.x;
    const float* src; short* dst; int off;
    if      (blk < 2048) { src = x;    dst = xb;          off = blk * 2048; }
    else if (blk < 2560) { src = pos;  dst = posb;        off = (blk - 2048) * 2048; }
    else if (blk < 2688) { src = Wq;   dst = wqkv;        off = (blk - 2560) * 2048; }
    else if (blk < 2816) { src = Wk;   dst = wqkv + 262144; off = (blk - 2688) * 2048; }
    else if (blk < 2944) { src = Wv;   dst = wqkv + 524288; off = (blk - 2816) * 2048; }
    else if (blk < 3072) { src = Wpos; dst = wpb;         off = (blk - 2944) * 2048; }
    else if (blk < 3200) { src = Wout; dst = wob;         off = (blk - 3072) * 2048; }
    else {
        int t = threadIdx.x;
        bqkv[t]        = bq[t];        bqkv[256 + t]  = bq[256 + t];
        bqkv[512 + t]  = bk[t];        bqkv[768 + t]  = bk[256 + t];
        bqkv[1024 + t] = bv[t];        bqkv[1280 + t] = bv[256 + t];
        return;
    }
    int i = off + threadIdx.x * 8;
    f4 a = *(const f4*)(src + i);
    f4 b = *(const f4*)(src + i + 4);
    bf16x8 o;
#pragma unroll
    for (int j = 0; j < 4; ++j) { o[j] = f2bf(a[j]); o[4 + j] = f2bf(b[j]); }
    *(bf16x8*)(dst + i) = o;
}

// ---------------- bf16 MFMA GEMM tile: C[128,128] = A@B^T + bias ---------------
template<int OUT_BF16>
static __device__ __forceinline__ void gemm_tile(
    short* As, short* Bs,
    const short* __restrict__ A, const short* __restrict__ B,
    const float* __restrict__ bias, void* __restrict__ Cv,
    int N, int K, int row0, int col0)
{
    const int tid = threadIdx.x, lane = tid & 63, wave = tid >> 6;
    const int col = lane & 15, quad = lane >> 4;
    const int wm = (wave >> 1) * 64, wn = (wave & 1) * 64;
    const int rl = lane & 15;

    const short* Abase = A + (size_t)(row0 + wave * 32 + rl) * K + (lane >> 4) * 8;
    const short* Bbase = B + (size_t)(col0 + wave * 32 + rl) * K + (lane >> 4) * 8;

    f32x4 acc[4][4];
#pragma unroll
    for (int i = 0; i < 4; ++i)
#pragma unroll
        for (int j = 0; j < 4; ++j) acc[i][j] = (f32x4){0.f, 0.f, 0.f, 0.f};

    for (int k0 = 0; k0 < K; k0 += 64) {
        __syncthreads();
#pragma unroll
        for (int c = 0; c < 2; ++c)
#pragma unroll
            for (int hf = 0; hf < 2; ++hf) {
                __builtin_amdgcn_global_load_lds((gptr_t)(Abase + (size_t)(16 * c) * K + k0 + hf * 32),
                                                 (lptr_t)(As + wave * 2048 + c * 1024 + hf * 512), 16, 0, 0);
                __builtin_amdgcn_global_load_lds((gptr_t)(Bbase + (size_t)(16 * c) * K + k0 + hf * 32),
                                                 (lptr_t)(Bs + wave * 2048 + c * 1024 + hf * 512), 16, 0, 0);
            }
        __syncthreads();
#pragma unroll
        for (int kt = 0; kt < 2; ++kt) {
            bf16x8 af[4], bfr[4];
#pragma unroll
            for (int mt = 0; mt < 4; ++mt)
                af[mt] = *(const bf16x8*)&As[((wm >> 4) + mt) * 1024 + (kt * 4 + quad) * 128 + col * 8];
#pragma unroll
            for (int nt = 0; nt < 4; ++nt)
                bfr[nt] = *(const bf16x8*)&Bs[((wn >> 4) + nt) * 1024 + (kt * 4 + quad) * 128 + col * 8];
#pragma unroll
            for (int mt = 0; mt < 4; ++mt)
#pragma unroll
                for (int nt = 0; nt < 4; ++nt)
                    acc[mt][nt] = __builtin_amdgcn_mfma_f32_16x16x32_bf16(af[mt], bfr[nt], acc[mt][nt], 0, 0, 0);
        }
    }

    float bv4[4];
#pragma unroll
    for (int nt = 0; nt < 4; ++nt)
        bv4[nt] = bias ? bias[col0 + wn + nt * 16 + col] : 0.f;
#pragma unroll
    for (int mt = 0; mt < 4; ++mt)
#pragma unroll
        for (int reg = 0; reg < 4; ++reg) {
            int r = row0 + wm + mt * 16 + quad * 4 + reg;
#pragma unroll
            for (int nt = 0; nt < 4; ++nt) {
                int c = col0 + wn + nt * 16 + col;
                float v = acc[mt][nt][reg] + bv4[nt];
                if (OUT_BF16) ((short*)Cv)[(size_t)r * N + c] = f2bf(v);
                else          ((float*)Cv)[(size_t)r * N + c] = v;
            }
        }
}

// QKV (768 tiles, XCD-swizzled) + pos (64 tiles) in one dispatch
__global__ __launch_bounds__(256) void gemm_qkv_pos(
    const short* __restrict__ xb, const short* __restrict__ wqkv,
    const float* __restrict__ bqkv, short* __restrict__ QKV,
    const short* __restrict__ posb, const short* __restrict__ wpb,
    short* __restrict__ Pm)
{
    __shared__ short As[8192], Bs[8192];
    const int bid = blockIdx.x;
    if (bid < 768) {
        const int xcd = bid & 7, s = bid >> 3;
        const int row = xcd * 8 + (s & 7), colt = s >> 3;   // row 0..63, colt 0..11
        gemm_tile<1>(As, Bs, xb, wqkv, bqkv, QKV, 1536, 512, row * 128, colt * 128);
    } else {
        const int t = bid - 768;
        gemm_tile<1>(As, Bs, posb, wpb, nullptr, Pm, 512, 512, (t / 4) * 128, (t % 4) * 128);
    }
}

__global__ __launch_bounds__(256) void gemm_out_kernel(
    const short* __restrict__ A, const short* __restrict__ B,
    const float* __restrict__ bias, float* __restrict__ C)
{
    __shared__ short As[8192], Bs[8192];
    const int bid = blockIdx.x;
    const int xcd = bid & 7, s = bid >> 3;
    const int row = xcd * 8 + (s & 7), colt = s >> 3;       // row 0..63, colt 0..3
    gemm_tile<0>(As, Bs, A, B, bias, C, 512, 512, row * 128, colt * 128);
}

// ---------------- fused: KP = K+P, cb = (log2e/8)*(u.k+vb.p), Vt transpose -----
__global__ __launch_bounds__(256) void kvprep_kernel(
    const short* __restrict__ qkv, const short* __restrict__ pm,
    const float* __restrict__ u, const float* __restrict__ vb,
    short* __restrict__ kp, short* __restrict__ vt, float* __restrict__ cb)
{
    __shared__ short tile[64][72];
    const int tid = threadIdx.x, lr = tid >> 2, lc = (tid & 3) * 16;
    const int bh = blockIdx.y, b = bh >> 3, h = bh & 7, s0 = blockIdx.x * 64;

    const short* kptr = qkv + (size_t)(b * T_SEQ + s0 + lr) * 1536 + 512 + h * DK + lc;
    const short* pptr = pm + (size_t)(s0 + lr) * NFEAT + h * DK + lc;
    const short* vptr = qkv + (size_t)(b * T_SEQ + s0 + lr) * 1536 + 1024 + h * DK + lc;
    bf16x8 k0_ = *(const bf16x8*)kptr,       k1_ = *(const bf16x8*)(kptr + 8);
    bf16x8 p0_ = *(const bf16x8*)pptr,       p1_ = *(const bf16x8*)(pptr + 8);
    bf16x8 v0_ = *(const bf16x8*)vptr,       v1_ = *(const bf16x8*)(vptr + 8);

    float c = 0.f;
    bf16x8 o0, o1;
#pragma unroll
    for (int j = 0; j < 8; ++j) {
        float kf = b2f(k0_[j]), pf = b2f(p0_[j]);
        o0[j] = f2bf(kf + pf);
        c += u[h * DK + lc + j] * kf + vb[h * DK + lc + j] * pf;
        float kf1 = b2f(k1_[j]), pf1 = b2f(p1_[j]);
        o1[j] = f2bf(kf1 + pf1);
        c += u[h * DK + lc + 8 + j] * kf1 + vb[h * DK + lc + 8 + j] * pf1;
    }
    short* kpd = kp + ((size_t)bh * T_SEQ + s0 + lr) * DK + lc;
    *(bf16x8*)kpd       = o0;
    *(bf16x8*)(kpd + 8) = o1;
    c += __shfl_xor(c, 1);
    c += __shfl_xor(c, 2);
    if ((tid & 3) == 0) cb[(size_t)bh * T_SEQ + s0 + lr] = LOG2E_8 * c;

    *(bf16x8*)&tile[lr][lc]     = v0_;
    *(bf16x8*)&tile[lr][lc + 8] = v1_;
    __syncthreads();
    short* dst = vt + (size_t)(bh * DK + lr) * T_SEQ + s0 + lc;
    bf16x8 t0_, t1_;
#pragma unroll
    for (int j = 0; j < 8; ++j) { t0_[j] = tile[lc + j][lr]; t1_[j] = tile[lc + 8 + j][lr]; }
    *(bf16x8*)dst       = t0_;
    *(bf16x8*)(dst + 8) = t1_;
}

// ---------------- flash attention: 128 Q-rows/block, 8 waves, bf16 MFMA --------
// XCD-swizzled grid; KP staged with key-permutation rho(r)=4*(r&15)+(r>>4) so each
// lane's 4 scores are 4 consecutive keys -> packed b64 P-writes + float4 cbias.
// Q-fragments loaded directly to registers (no Qs tile): LDS 37 KB -> 4 blocks/CU.
__global__ __launch_bounds__(512, 8) void attn_kernel(
    const short* __restrict__ qkv, const short* __restrict__ kp,
    const short* __restrict__ vt, const float* __restrict__ cb,
    short* __restrict__ attO)
{
    __shared__ __align__(16) short KPs[64][72], Vts[64][72], Ps[8][16][72];
    __shared__ float cs[64];
    const int tid = threadIdx.x, lane = tid & 63, wave = tid >> 6;
    const int col = lane & 15, quad = lane >> 4;
    const int idx = blockIdx.x;
    const int xcd = idx & 7, slot = idx >> 3;
    const int bh = (slot >> 4) * 8 + xcd;         // 4 bh per XCD -> 2MB KV in L2
    const int t0 = (slot & 15) * 128;
    const int b = bh >> 3, h = bh & 7;

    // Q fragments straight from global (each wave reads only its own 16 rows)
    const short* qbase = qkv + (size_t)(b * T_SEQ + t0 + wave * 16 + col) * 1536 + h * DK + quad * 8;
    bf16x8 qa0 = *(const bf16x8*)qbase;
    bf16x8 qa1 = *(const bf16x8*)(qbase + 32);

    const int lr8 = tid >> 3, lc8 = (tid & 7) * 8;     // 64x64 staging
    const int rho = 4 * (lr8 & 15) + (lr8 >> 4);       // key permutation for KP rows

    // prime the register pipeline (s0 = 0)
    bf16x8 kpr = *(const bf16x8*)(kp + ((size_t)bh * T_SEQ + rho) * DK + lc8);
    bf16x8 vtr = *(const bf16x8*)(vt + ((size_t)(bh * DK + lr8)) * T_SEQ + lc8);
    float cbr = (tid < 64) ? cb[(size_t)bh * T_SEQ + tid] : 0.f;

    f32x4 Oacc[4];
    float lsum[4] = {0.f, 0.f, 0.f, 0.f};
#pragma unroll
    for (int i = 0; i < 4; ++i) Oacc[i] = (f32x4){0.f, 0.f, 0.f, 0.f};

    for (int s0 = 0; s0 < T_SEQ; s0 += 64) {
        __syncthreads();                 // prev iter's KPs/Vts reads done
        *(bf16x8*)&KPs[lr8][lc8] = kpr;
        *(bf16x8*)&Vts[lr8][lc8] = vtr;
        if (tid < 64) cs[tid] = cbr;
        __syncthreads();

        // prefetch next tile (wraps harmlessly on last iter)
        const int sn = (s0 + 64) & (T_SEQ - 1);
        kpr = *(const bf16x8*)(kp + ((size_t)bh * T_SEQ + sn + rho) * DK + lc8);
        vtr = *(const bf16x8*)(vt + ((size_t)(bh * DK + lr8)) * T_SEQ + sn + lc8);
        if (tid < 64) cbr = cb[(size_t)bh * T_SEQ + sn + tid];

        f32x4 S[4];
#pragma unroll
        for (int nt = 0; nt < 4; ++nt) S[nt] = (f32x4){0.f, 0.f, 0.f, 0.f};
#pragma unroll
        for (int nt = 0; nt < 4; ++nt) {
            bf16x8 b0 = *(const bf16x8*)&KPs[nt * 16 + col][quad * 8];
            S[nt] = __builtin_amdgcn_mfma_f32_16x16x32_bf16(qa0, b0, S[nt], 0, 0, 0);
            bf16x8 b1 = *(const bf16x8*)&KPs[nt * 16 + col][32 + quad * 8];
            S[nt] = __builtin_amdgcn_mfma_f32_16x16x32_bf16(qa1, b1, S[nt], 0, 0, 0);
        }
        // lane's score (nt,reg) = key 4*col+nt (via rho) -> packed writes
        const f4 cv = *(const f4*)&cs[4 * col];
#pragma unroll
        for (int reg = 0; reg < 4; ++reg) {
            float e0 = __builtin_amdgcn_exp2f(fmaf(S[0][reg], LOG2E_8, cv[0]));
            float e1 = __builtin_amdgcn_exp2f(fmaf(S[1][reg], LOG2E_8, cv[1]));
            float e2 = __builtin_amdgcn_exp2f(fmaf(S[2][reg], LOG2E_8, cv[2]));
            float e3 = __builtin_amdgcn_exp2f(fmaf(S[3][reg], LOG2E_8, cv[3]));
            lsum[reg] += (e0 + e1) + (e2 + e3);
            i32x2 pw; pw[0] = pkbf(e0, e1); pw[1] = pkbf(e2, e3);
            *(i32x2*)&Ps[wave][quad * 4 + reg][4 * col] = pw;
        }
        // NO barrier: Ps is strictly per-wave
#pragma unroll
        for (int kt = 0; kt < 2; ++kt) {
            bf16x8 pa = *(const bf16x8*)&Ps[wave][col][kt * 32 + quad * 8];
#pragma unroll
            for (int dt = 0; dt < 4; ++dt) {
                bf16x8 vb = *(const bf16x8*)&Vts[dt * 16 + col][kt * 32 + quad * 8];
                Oacc[dt] = __builtin_amdgcn_mfma_f32_16x16x32_bf16(pa, vb, Oacc[dt], 0, 0, 0);
            }
        }
    }
#pragma unroll
    for (int reg = 0; reg < 4; ++reg) {
        float l = lsum[reg];
#pragma unroll
        for (int off = 1; off < 16; off <<= 1) l += __shfl_xor(l, off);
        float inv = 1.f / l;
        int t = t0 + wave * 16 + quad * 4 + reg;
        short* op = attO + (size_t)(b * T_SEQ + t) * NFEAT + h * DK;
#pragma unroll
        for (int dt = 0; dt < 4; ++dt)
            op[dt * 16 + col] = f2bf(Oacc[dt][reg] * inv);
    }
}

extern "C" void kernel_launch(void* const* d_in, const int* in_sizes, int n_in,
                              void* d_out, int out_size, void* d_ws, size_t ws_size,
                              hipStream_t stream)
{
    const float* x    = (const float*)d_in[0];
    const float* pos  = (const float*)d_in[1];
    const float* Wq   = (const float*)d_in[2];
    const float* bq   = (const float*)d_in[3];
    const float* Wk   = (const float*)d_in[4];
    const float* bk   = (const float*)d_in[5];
    const float* Wv   = (const float*)d_in[6];
    const float* bv   = (const float*)d_in[7];
    const float* Wpos = (const float*)d_in[8];
    const float* Wout = (const float*)d_in[9];
    const float* bout = (const float*)d_in[10];
    const float* pbu  = (const float*)d_in[11];
    const float* pbv  = (const float*)d_in[12];
    float* out = (float*)d_out;

    short* xb   = (short*)d_ws;            // 4,194,304
    short* posb = xb   + 4194304;          // 1,048,576
    short* wqkv = posb + 1048576;          //   786,432
    short* wpb  = wqkv + 786432;           //   262,144
    short* wob  = wpb  + 262144;           //   262,144
    short* QKV  = wob  + 262144;           // 12,582,912  [8192][1536] (Q|K|V)
    short* Pm   = QKV  + 12582912;         // 1,048,576   [2048][512]
    short* KP   = Pm   + 1048576;          // 4,194,304   [bh][s][64]
    short* Vt   = KP   + 4194304;          // 4,194,304   [bh][d][t]
    short* AttO = Vt   + 4194304;          // 4,194,304   [8192][512]
    float* bqkv = (float*)(AttO + 4194304);
    float* Cb   = bqkv + 1536;             // 65,536

    cvt_kernel<<<dim3(3201), dim3(256), 0, stream>>>(x, pos, Wq, Wk, Wv, Wpos, Wout, bq, bk, bv,
                                                     xb, posb, wqkv, wpb, wob, bqkv);
    gemm_qkv_pos<<<dim3(832), dim3(256), 0, stream>>>(xb, wqkv, bqkv, QKV, posb, wpb, Pm);
    kvprep_kernel<<<dim3(T_SEQ / 64, BATCH * NHEAD), dim3(256), 0, stream>>>(QKV, Pm, pbu, pbv, KP, Vt, Cb);
    attn_kernel<<<dim3(512), dim3(512), 0, stream>>>(QKV, KP, Vt, Cb, AttO);
    gemm_out_kernel<<<dim3(256), dim3(256), 0, stream>>>(AttO, wob, bout, out);
}

// Round 7
// 226.870 us; speedup vs baseline: 1.0710x; 1.0710x over previous
//
#include <hip/hip_runtime.h>

typedef float f4 __attribute__((ext_vector_type(4)));
typedef __attribute__((ext_vector_type(8))) short bf16x8;
typedef __attribute__((ext_vector_type(4))) float f32x4;
typedef __attribute__((ext_vector_type(2))) int i32x2;

#define T_SEQ 2048
#define NFEAT 512
#define NHEAD 8
#define DK    64
#define BATCH 4

using gptr_t = const __attribute__((address_space(1))) void*;
using lptr_t = __attribute__((address_space(3))) void*;

#define LOG2E_8 0.18033688011f   // 0.125 * log2(e)

static __device__ __forceinline__ short f2bf(float f) {
    unsigned u = __builtin_bit_cast(unsigned, f);
    u += 0x7fff + ((u >> 16) & 1);          // round-to-nearest-even
    return (short)(u >> 16);
}
static __device__ __forceinline__ float b2f(short s) {
    unsigned u = ((unsigned)(unsigned short)s) << 16;
    return __builtin_bit_cast(float, u);
}
// pack two floats -> two bf16 (cheap round) in one int
static __device__ __forceinline__ int pkbf(float a, float b) {
    unsigned ua = __builtin_bit_cast(unsigned, a) + 0x8000u;
    unsigned ub = __builtin_bit_cast(unsigned, b) + 0x8000u;
    return (int)((ua >> 16) | (ub & 0xFFFF0000u));
}

// ---------------- fused fp32->bf16 conversion + weight/bias packing -------------
__global__ __launch_bounds__(256) void cvt_kernel(
    const float* __restrict__ x, const float* __restrict__ pos,
    const float* __restrict__ Wq, const float* __restrict__ Wk, const float* __restrict__ Wv,
    const float* __restrict__ Wpos, const float* __restrict__ Wout,
    const float* __restrict__ bq, const float* __restrict__ bk, const float* __restrict__ bv,
    short* __restrict__ xb, short* __restrict__ posb, short* __restrict__ wqkv,
    short* __restrict__ wpb, short* __restrict__ wob, float* __restrict__ bqkv)
{
    const int blk = blockIdx.x;
    const float* src; short* dst; int off;
    if      (blk < 2048) { src = x;    dst = xb;          off = blk * 2048; }
    else if (blk < 2560) { src = pos;  dst = posb;        off = (blk - 2048) * 2048; }
    else if (blk < 2688) { src = Wq;   dst = wqkv;        off = (blk - 2560) * 2048; }
    else if (blk < 2816) { src = Wk;   dst = wqkv + 262144; off = (blk - 2688) * 2048; }
    else if (blk < 2944) { src = Wv;   dst = wqkv + 524288; off = (blk - 2816) * 2048; }
    else if (blk < 3072) { src = Wpos; dst = wpb;         off = (blk - 2944) * 2048; }
    else if (blk < 3200) { src = Wout; dst = wob;         off = (blk - 3072) * 2048; }
    else {
        int t = threadIdx.x;
        bqkv[t]        = bq[t];        bqkv[256 + t]  = bq[256 + t];
        bqkv[512 + t]  = bk[t];        bqkv[768 + t]  = bk[256 + t];
        bqkv[1024 + t] = bv[t];        bqkv[1280 + t] = bv[256 + t];
        return;
    }
    int i = off + threadIdx.x * 8;
    f4 a = *(const f4*)(src + i);
    f4 b = *(const f4*)(src + i + 4);
    bf16x8 o;
#pragma unroll
    for (int j = 0; j < 4; ++j) { o[j] = f2bf(a[j]); o[4 + j] = f2bf(b[j]); }
    *(bf16x8*)(dst + i) = o;
}

// ---------------- bf16 MFMA GEMM tile: C[128,128] = A@B^T + bias ---------------
template<int OUT_BF16>
static __device__ __forceinline__ void gemm_tile(
    short* As, short* Bs,
    const short* __restrict__ A, const short* __restrict__ B,
    const float* __restrict__ bias, void* __restrict__ Cv,
    int N, int K, int row0, int col0)
{
    const int tid = threadIdx.x, lane = tid & 63, wave = tid >> 6;
    const int col = lane & 15, quad = lane >> 4;
    const int wm = (wave >> 1) * 64, wn = (wave & 1) * 64;
    const int rl = lane & 15;

    const short* Abase = A + (size_t)(row0 + wave * 32 + rl) * K + (lane >> 4) * 8;
    const short* Bbase = B + (size_t)(col0 + wave * 32 + rl) * K + (lane >> 4) * 8;

    f32x4 acc[4][4];
#pragma unroll
    for (int i = 0; i < 4; ++i)
#pragma unroll
        for (int j = 0; j < 4; ++j) acc[i][j] = (f32x4){0.f, 0.f, 0.f, 0.f};

    for (int k0 = 0; k0 < K; k0 += 64) {
        __syncthreads();
#pragma unroll
        for (int c = 0; c < 2; ++c)
#pragma unroll
            for (int hf = 0; hf < 2; ++hf) {
                __builtin_amdgcn_global_load_lds((gptr_t)(Abase + (size_t)(16 * c) * K + k0 + hf * 32),
                                                 (lptr_t)(As + wave * 2048 + c * 1024 + hf * 512), 16, 0, 0);
                __builtin_amdgcn_global_load_lds((gptr_t)(Bbase + (size_t)(16 * c) * K + k0 + hf * 32),
                                                 (lptr_t)(Bs + wave * 2048 + c * 1024 + hf * 512), 16, 0, 0);
            }
        __syncthreads();
#pragma unroll
        for (int kt = 0; kt < 2; ++kt) {
            bf16x8 af[4], bfr[4];
#pragma unroll
            for (int mt = 0; mt < 4; ++mt)
                af[mt] = *(const bf16x8*)&As[((wm >> 4) + mt) * 1024 + (kt * 4 + quad) * 128 + col * 8];
#pragma unroll
            for (int nt = 0; nt < 4; ++nt)
                bfr[nt] = *(const bf16x8*)&Bs[((wn >> 4) + nt) * 1024 + (kt * 4 + quad) * 128 + col * 8];
#pragma unroll
            for (int mt = 0; mt < 4; ++mt)
#pragma unroll
                for (int nt = 0; nt < 4; ++nt)
                    acc[mt][nt] = __builtin_amdgcn_mfma_f32_16x16x32_bf16(af[mt], bfr[nt], acc[mt][nt], 0, 0, 0);
        }
    }

    float bv4[4];
#pragma unroll
    for (int nt = 0; nt < 4; ++nt)
        bv4[nt] = bias ? bias[col0 + wn + nt * 16 + col] : 0.f;
#pragma unroll
    for (int mt = 0; mt < 4; ++mt)
#pragma unroll
        for (int reg = 0; reg < 4; ++reg) {
            int r = row0 + wm + mt * 16 + quad * 4 + reg;
#pragma unroll
            for (int nt = 0; nt < 4; ++nt) {
                int c = col0 + wn + nt * 16 + col;
                float v = acc[mt][nt][reg] + bv4[nt];
                if (OUT_BF16) ((short*)Cv)[(size_t)r * N + c] = f2bf(v);
                else          ((float*)Cv)[(size_t)r * N + c] = v;
            }
        }
}

// QKV (768 tiles, XCD-swizzled) + pos (64 tiles) in one dispatch
__global__ __launch_bounds__(256) void gemm_qkv_pos(
    const short* __restrict__ xb, const short* __restrict__ wqkv,
    const float* __restrict__ bqkv, short* __restrict__ QKV,
    const short* __restrict__ posb, const short* __restrict__ wpb,
    short* __restrict__ Pm)
{
    __shared__ short As[8192], Bs[8192];
    const int bid = blockIdx.x;
    if (bid < 768) {
        const int xcd = bid & 7, s = bid >> 3;
        const int row = xcd * 8 + (s & 7), colt = s >> 3;   // row 0..63, colt 0..11
        gemm_tile<1>(As, Bs, xb, wqkv, bqkv, QKV, 1536, 512, row * 128, colt * 128);
    } else {
        const int t = bid - 768;
        gemm_tile<1>(As, Bs, posb, wpb, nullptr, Pm, 512, 512, (t / 4) * 128, (t % 4) * 128);
    }
}

__global__ __launch_bounds__(256) void gemm_out_kernel(
    const short* __restrict__ A, const short* __restrict__ B,
    const float* __restrict__ bias, float* __restrict__ C)
{
    __shared__ short As[8192], Bs[8192];
    const int bid = blockIdx.x;
    const int xcd = bid & 7, s = bid >> 3;
    const int row = xcd * 8 + (s & 7), colt = s >> 3;       // row 0..63, colt 0..3
    gemm_tile<0>(As, Bs, A, B, bias, C, 512, 512, row * 128, colt * 128);
}

// ---------------- fused: KP = K+P, cb = (log2e/8)*(u.k+vb.p), Vt transpose -----
__global__ __launch_bounds__(256) void kvprep_kernel(
    const short* __restrict__ qkv, const short* __restrict__ pm,
    const float* __restrict__ u, const float* __restrict__ vb,
    short* __restrict__ kp, short* __restrict__ vt, float* __restrict__ cb)
{
    __shared__ short tile[64][72];
    const int tid = threadIdx.x, lr = tid >> 2, lc = (tid & 3) * 16;
    const int bh = blockIdx.y, b = bh >> 3, h = bh & 7, s0 = blockIdx.x * 64;

    const short* kptr = qkv + (size_t)(b * T_SEQ + s0 + lr) * 1536 + 512 + h * DK + lc;
    const short* pptr = pm + (size_t)(s0 + lr) * NFEAT + h * DK + lc;
    const short* vptr = qkv + (size_t)(b * T_SEQ + s0 + lr) * 1536 + 1024 + h * DK + lc;
    bf16x8 k0_ = *(const bf16x8*)kptr,       k1_ = *(const bf16x8*)(kptr + 8);
    bf16x8 p0_ = *(const bf16x8*)pptr,       p1_ = *(const bf16x8*)(pptr + 8);
    bf16x8 v0_ = *(const bf16x8*)vptr,       v1_ = *(const bf16x8*)(vptr + 8);

    float c = 0.f;
    bf16x8 o0, o1;
#pragma unroll
    for (int j = 0; j < 8; ++j) {
        float kf = b2f(k0_[j]), pf = b2f(p0_[j]);
        o0[j] = f2bf(kf + pf);
        c += u[h * DK + lc + j] * kf + vb[h * DK + lc + j] * pf;
        float kf1 = b2f(k1_[j]), pf1 = b2f(p1_[j]);
        o1[j] = f2bf(kf1 + pf1);
        c += u[h * DK + lc + 8 + j] * kf1 + vb[h * DK + lc + 8 + j] * pf1;
    }
    short* kpd = kp + ((size_t)bh * T_SEQ + s0 + lr) * DK + lc;
    *(bf16x8*)kpd       = o0;
    *(bf16x8*)(kpd + 8) = o1;
    c += __shfl_xor(c, 1);
    c += __shfl_xor(c, 2);
    if ((tid & 3) == 0) cb[(size_t)bh * T_SEQ + s0 + lr] = LOG2E_8 * c;

    *(bf16x8*)&tile[lr][lc]     = v0_;
    *(bf16x8*)&tile[lr][lc + 8] = v1_;
    __syncthreads();
    short* dst = vt + (size_t)(bh * DK + lr) * T_SEQ + s0 + lc;
    bf16x8 t0_, t1_;
#pragma unroll
    for (int j = 0; j < 8; ++j) { t0_[j] = tile[lc + j][lr]; t1_[j] = tile[lc + 8 + j][lr]; }
    *(bf16x8*)dst       = t0_;
    *(bf16x8*)(dst + 8) = t1_;
}

// ---------------- flash attention: 4 waves x 32 Q-rows, bf16 MFMA --------------
// LDS-BW fix: each wave owns TWO 16-row A-groups sharing every KP/Vt B-fragment
// read -> LDS bytes per MFMA-FLOP drops ~35%. XCD swizzle + rho key permutation
// (packed b64 P-writes) + register prefetch. VGPR capped at 128 (no spill!).
__global__ __launch_bounds__(256, 4) void attn_kernel(
    const short* __restrict__ qkv, const short* __restrict__ kp,
    const short* __restrict__ vt, const float* __restrict__ cb,
    short* __restrict__ attO)
{
    __shared__ __align__(16) short KPs[64][72], Vts[64][72], Ps[4][32][72];
    __shared__ float cs[64];
    const int tid = threadIdx.x, lane = tid & 63, wave = tid >> 6;   // 4 waves
    const int col = lane & 15, quad = lane >> 4;
    const int idx = blockIdx.x;
    const int xcd = idx & 7, slot = idx >> 3;
    const int bh = (slot >> 4) * 8 + xcd;         // 4 bh per XCD -> 2MB KV in L2
    const int t0 = (slot & 15) * 128;
    const int b = bh >> 3, h = bh & 7;

    // Q fragments straight from global: rows t0 + wave*32 + g*16 + col
    bf16x8 qa[2][2];
#pragma unroll
    for (int g = 0; g < 2; ++g) {
        const short* qb = qkv + (size_t)(b * T_SEQ + t0 + wave * 32 + g * 16 + col) * 1536 + h * DK + quad * 8;
        qa[g][0] = *(const bf16x8*)qb;
        qa[g][1] = *(const bf16x8*)(qb + 32);
    }

    const int lr  = tid >> 2;             // 0..63 staging row
    const int lcq = (tid & 3) * 16;       // 0,16,32,48
    const int rho = 4 * (lr & 15) + (lr >> 4);   // key permutation for KP rows

    const short* kpbase = kp + (size_t)bh * T_SEQ * DK;
    const short* vtbase = vt + (size_t)bh * DK * T_SEQ;

    // prime the register pipeline (s0 = 0)
    bf16x8 kpr0 = *(const bf16x8*)(kpbase + (size_t)rho * DK + lcq);
    bf16x8 kpr1 = *(const bf16x8*)(kpbase + (size_t)rho * DK + lcq + 8);
    bf16x8 vtr0 = *(const bf16x8*)(vtbase + (size_t)lr * T_SEQ + lcq);
    bf16x8 vtr1 = *(const bf16x8*)(vtbase + (size_t)lr * T_SEQ + lcq + 8);
    float cbr = (tid < 64) ? cb[(size_t)bh * T_SEQ + tid] : 0.f;

    f32x4 Oacc[2][4];
    float lsum[2][4];
#pragma unroll
    for (int g = 0; g < 2; ++g)
#pragma unroll
        for (int i = 0; i < 4; ++i) { Oacc[g][i] = (f32x4){0.f, 0.f, 0.f, 0.f}; lsum[g][i] = 0.f; }

    for (int s0 = 0; s0 < T_SEQ; s0 += 64) {
        __syncthreads();                 // prev iter's KPs/Vts reads done
        *(bf16x8*)&KPs[lr][lcq]     = kpr0;
        *(bf16x8*)&KPs[lr][lcq + 8] = kpr1;
        *(bf16x8*)&Vts[lr][lcq]     = vtr0;
        *(bf16x8*)&Vts[lr][lcq + 8] = vtr1;
        if (tid < 64) cs[tid] = cbr;
        __syncthreads();

        // prefetch next tile (wraps harmlessly on last iter)
        const int sn = (s0 + 64) & (T_SEQ - 1);
        kpr0 = *(const bf16x8*)(kpbase + (size_t)(sn + rho) * DK + lcq);
        kpr1 = *(const bf16x8*)(kpbase + (size_t)(sn + rho) * DK + lcq + 8);
        vtr0 = *(const bf16x8*)(vtbase + (size_t)lr * T_SEQ + sn + lcq);
        vtr1 = *(const bf16x8*)(vtbase + (size_t)lr * T_SEQ + sn + lcq + 8);
        if (tid < 64) cbr = cb[(size_t)bh * T_SEQ + sn + tid];

        // QK: B-fragments read ONCE, used by both row-groups
        f32x4 S[2][4];
#pragma unroll
        for (int g = 0; g < 2; ++g)
#pragma unroll
            for (int nt = 0; nt < 4; ++nt) S[g][nt] = (f32x4){0.f, 0.f, 0.f, 0.f};
#pragma unroll
        for (int nt = 0; nt < 4; ++nt) {
            bf16x8 b0 = *(const bf16x8*)&KPs[nt * 16 + col][quad * 8];
            bf16x8 b1 = *(const bf16x8*)&KPs[nt * 16 + col][32 + quad * 8];
            S[0][nt] = __builtin_amdgcn_mfma_f32_16x16x32_bf16(qa[0][0], b0, S[0][nt], 0, 0, 0);
            S[1][nt] = __builtin_amdgcn_mfma_f32_16x16x32_bf16(qa[1][0], b0, S[1][nt], 0, 0, 0);
            S[0][nt] = __builtin_amdgcn_mfma_f32_16x16x32_bf16(qa[0][1], b1, S[0][nt], 0, 0, 0);
            S[1][nt] = __builtin_amdgcn_mfma_f32_16x16x32_bf16(qa[1][1], b1, S[1][nt], 0, 0, 0);
        }
        // lane's score (nt,reg) = key 4*col+nt (via rho) -> packed b64 writes
        const f4 cv = *(const f4*)&cs[4 * col];
#pragma unroll
        for (int g = 0; g < 2; ++g)
#pragma unroll
            for (int reg = 0; reg < 4; ++reg) {
                float e0 = __builtin_amdgcn_exp2f(fmaf(S[0 + g * 0][0][reg], LOG2E_8, cv[0]));
                // (indexing spelled out below to keep S[g][nt])
                e0 = __builtin_amdgcn_exp2f(fmaf(S[g][0][reg], LOG2E_8, cv[0]));
                float e1 = __builtin_amdgcn_exp2f(fmaf(S[g][1][reg], LOG2E_8, cv[1]));
                float e2 = __builtin_amdgcn_exp2f(fmaf(S[g][2][reg], LOG2E_8, cv[2]));
                float e3 = __builtin_amdgcn_exp2f(fmaf(S[g][3][reg], LOG2E_8, cv[3]));
                lsum[g][reg] += (e0 + e1) + (e2 + e3);
                i32x2 pw; pw[0] = pkbf(e0, e1); pw[1] = pkbf(e2, e3);
                *(i32x2*)&Ps[wave][g * 16 + quad * 4 + reg][4 * col] = pw;
            }
        // PV: Vt fragments read ONCE, used by both row-groups (no barrier: per-wave Ps)
#pragma unroll
        for (int kt = 0; kt < 2; ++kt) {
            bf16x8 pa0 = *(const bf16x8*)&Ps[wave][col][kt * 32 + quad * 8];
            bf16x8 pa1 = *(const bf16x8*)&Ps[wave][16 + col][kt * 32 + quad * 8];
#pragma unroll
            for (int dt = 0; dt < 4; ++dt) {
                bf16x8 vb = *(const bf16x8*)&Vts[dt * 16 + col][kt * 32 + quad * 8];
                Oacc[0][dt] = __builtin_amdgcn_mfma_f32_16x16x32_bf16(pa0, vb, Oacc[0][dt], 0, 0, 0);
                Oacc[1][dt] = __builtin_amdgcn_mfma_f32_16x16x32_bf16(pa1, vb, Oacc[1][dt], 0, 0, 0);
            }
        }
    }
#pragma unroll
    for (int g = 0; g < 2; ++g)
#pragma unroll
        for (int reg = 0; reg < 4; ++reg) {
            float l = lsum[g][reg];
#pragma unroll
            for (int off = 1; off < 16; off <<= 1) l += __shfl_xor(l, off);
            float inv = 1.f / l;
            int t = t0 + wave * 32 + g * 16 + quad * 4 + reg;
            short* op = attO + (size_t)(b * T_SEQ + t) * NFEAT + h * DK;
#pragma unroll
            for (int dt = 0; dt < 4; ++dt)
                op[dt * 16 + col] = f2bf(Oacc[g][dt][reg] * inv);
        }
}

extern "C" void kernel_launch(void* const* d_in, const int* in_sizes, int n_in,
                              void* d_out, int out_size, void* d_ws, size_t ws_size,
                              hipStream_t stream)
{
    const float* x    = (const float*)d_in[0];
    const float* pos  = (const float*)d_in[1];
    const float* Wq   = (const float*)d_in[2];
    const float* bq   = (const float*)d_in[3];
    const float* Wk   = (const float*)d_in[4];
    const float* bk   = (const float*)d_in[5];
    const float* Wv   = (const float*)d_in[6];
    const float* bv   = (const float*)d_in[7];
    const float* Wpos = (const float*)d_in[8];
    const float* Wout = (const float*)d_in[9];
    const float* bout = (const float*)d_in[10];
    const float* pbu  = (const float*)d_in[11];
    const float* pbv  = (const float*)d_in[12];
    float* out = (float*)d_out;

    short* xb   = (short*)d_ws;            // 4,194,304
    short* posb = xb   + 4194304;          // 1,048,576
    short* wqkv = posb + 1048576;          //   786,432
    short* wpb  = wqkv + 786432;           //   262,144
    short* wob  = wpb  + 262144;           //   262,144
    short* QKV  = wob  + 262144;           // 12,582,912  [8192][1536] (Q|K|V)
    short* Pm   = QKV  + 12582912;         // 1,048,576   [2048][512]
    short* KP   = Pm   + 1048576;          // 4,194,304   [bh][s][64]
    short* Vt   = KP   + 4194304;          // 4,194,304   [bh][d][t]
    short* AttO = Vt   + 4194304;          // 4,194,304   [8192][512]
    float* bqkv = (float*)(AttO + 4194304);
    float* Cb   = bqkv + 1536;             // 65,536

    cvt_kernel<<<dim3(3201), dim3(256), 0, stream>>>(x, pos, Wq, Wk, Wv, Wpos, Wout, bq, bk, bv,
                                                     xb, posb, wqkv, wpb, wob, bqkv);
    gemm_qkv_pos<<<dim3(832), dim3(256), 0, stream>>>(xb, wqkv, bqkv, QKV, posb, wpb, Pm);
    kvprep_kernel<<<dim3(T_SEQ / 64, BATCH * NHEAD), dim3(256), 0, stream>>>(QKV, Pm, pbu, pbv, KP, Vt, Cb);
    attn_kernel<<<dim3(512), dim3(256), 0, stream>>>(QKV, KP, Vt, Cb, AttO);
    gemm_out_kernel<<<dim3(256), dim3(256), 0, stream>>>(AttO, wob, bout, out);
}

// Round 8
// 214.029 us; speedup vs baseline: 1.1353x; 1.0600x over previous
//
#include <hip/hip_runtime.h>

typedef float f4 __attribute__((ext_vector_type(4)));
typedef __attribute__((ext_vector_type(8))) short bf16x8;
typedef __attribute__((ext_vector_type(4))) float f32x4;
typedef __attribute__((ext_vector_type(2))) int i32x2;

#define T_SEQ 2048
#define NFEAT 512
#define NHEAD 8
#define DK    64
#define BATCH 4

using gptr_t = const __attribute__((address_space(1))) void*;
using lptr_t = __attribute__((address_space(3))) void*;

#define LOG2E_8 0.18033688011f   // 0.125 * log2(e)

static __device__ __forceinline__ short f2bf(float f) {
    unsigned u = __builtin_bit_cast(unsigned, f);
    u += 0x7fff + ((u >> 16) & 1);          // round-to-nearest-even
    return (short)(u >> 16);
}
static __device__ __forceinline__ float b2f(short s) {
    unsigned u = ((unsigned)(unsigned short)s) << 16;
    return __builtin_bit_cast(float, u);
}
// pack two floats -> two bf16 (cheap round) in one int
static __device__ __forceinline__ int pkbf(float a, float b) {
    unsigned ua = __builtin_bit_cast(unsigned, a) + 0x8000u;
    unsigned ub = __builtin_bit_cast(unsigned, b) + 0x8000u;
    return (int)((ua >> 16) | (ub & 0xFFFF0000u));
}

// ---------------- fused fp32->bf16 conversion + weight/bias packing -------------
__global__ __launch_bounds__(256) void cvt_kernel(
    const float* __restrict__ x, const float* __restrict__ pos,
    const float* __restrict__ Wq, const float* __restrict__ Wk, const float* __restrict__ Wv,
    const float* __restrict__ Wpos, const float* __restrict__ Wout,
    const float* __restrict__ bq, const float* __restrict__ bk, const float* __restrict__ bv,
    short* __restrict__ xb, short* __restrict__ posb, short* __restrict__ wqkv,
    short* __restrict__ wpb, short* __restrict__ wob, float* __restrict__ bqkv)
{
    const int blk = blockIdx.x;
    const float* src; short* dst; int off;
    if      (blk < 2048) { src = x;    dst = xb;          off = blk * 2048; }
    else if (blk < 2560) { src = pos;  dst = posb;        off = (blk - 2048) * 2048; }
    else if (blk < 2688) { src = Wq;   dst = wqkv;        off = (blk - 2560) * 2048; }
    else if (blk < 2816) { src = Wk;   dst = wqkv + 262144; off = (blk - 2688) * 2048; }
    else if (blk < 2944) { src = Wv;   dst = wqkv + 524288; off = (blk - 2816) * 2048; }
    else if (blk < 3072) { src = Wpos; dst = wpb;         off = (blk - 2944) * 2048; }
    else if (blk < 3200) { src = Wout; dst = wob;         off = (blk - 3072) * 2048; }
    else {
        int t = threadIdx.x;
        bqkv[t]        = bq[t];        bqkv[256 + t]  = bq[256 + t];
        bqkv[512 + t]  = bk[t];        bqkv[768 + t]  = bk[256 + t];
        bqkv[1024 + t] = bv[t];        bqkv[1280 + t] = bv[256 + t];
        return;
    }
    int i = off + threadIdx.x * 8;
    f4 a = *(const f4*)(src + i);
    f4 b = *(const f4*)(src + i + 4);
    bf16x8 o;
#pragma unroll
    for (int j = 0; j < 4; ++j) { o[j] = f2bf(a[j]); o[4 + j] = f2bf(b[j]); }
    *(bf16x8*)(dst + i) = o;
}

// ---------------- bf16 MFMA GEMM tile: C[128,128] = A@B^T + bias ---------------
template<int OUT_BF16>
static __device__ __forceinline__ void gemm_tile(
    short* As, short* Bs,
    const short* __restrict__ A, const short* __restrict__ B,
    const float* __restrict__ bias, void* __restrict__ Cv,
    int N, int K, int row0, int col0)
{
    const int tid = threadIdx.x, lane = tid & 63, wave = tid >> 6;
    const int col = lane & 15, quad = lane >> 4;
    const int wm = (wave >> 1) * 64, wn = (wave & 1) * 64;
    const int rl = lane & 15;

    const short* Abase = A + (size_t)(row0 + wave * 32 + rl) * K + (lane >> 4) * 8;
    const short* Bbase = B + (size_t)(col0 + wave * 32 + rl) * K + (lane >> 4) * 8;

    f32x4 acc[4][4];
#pragma unroll
    for (int i = 0; i < 4; ++i)
#pragma unroll
        for (int j = 0; j < 4; ++j) acc[i][j] = (f32x4){0.f, 0.f, 0.f, 0.f};

    for (int k0 = 0; k0 < K; k0 += 64) {
        __syncthreads();
#pragma unroll
        for (int c = 0; c < 2; ++c)
#pragma unroll
            for (int hf = 0; hf < 2; ++hf) {
                __builtin_amdgcn_global_load_lds((gptr_t)(Abase + (size_t)(16 * c) * K + k0 + hf * 32),
                                                 (lptr_t)(As + wave * 2048 + c * 1024 + hf * 512), 16, 0, 0);
                __builtin_amdgcn_global_load_lds((gptr_t)(Bbase + (size_t)(16 * c) * K + k0 + hf * 32),
                                                 (lptr_t)(Bs + wave * 2048 + c * 1024 + hf * 512), 16, 0, 0);
            }
        __syncthreads();
#pragma unroll
        for (int kt = 0; kt < 2; ++kt) {
            bf16x8 af[4], bfr[4];
#pragma unroll
            for (int mt = 0; mt < 4; ++mt)
                af[mt] = *(const bf16x8*)&As[((wm >> 4) + mt) * 1024 + (kt * 4 + quad) * 128 + col * 8];
#pragma unroll
            for (int nt = 0; nt < 4; ++nt)
                bfr[nt] = *(const bf16x8*)&Bs[((wn >> 4) + nt) * 1024 + (kt * 4 + quad) * 128 + col * 8];
#pragma unroll
            for (int mt = 0; mt < 4; ++mt)
#pragma unroll
                for (int nt = 0; nt < 4; ++nt)
                    acc[mt][nt] = __builtin_amdgcn_mfma_f32_16x16x32_bf16(af[mt], bfr[nt], acc[mt][nt], 0, 0, 0);
        }
    }

    float bv4[4];
#pragma unroll
    for (int nt = 0; nt < 4; ++nt)
        bv4[nt] = bias ? bias[col0 + wn + nt * 16 + col] : 0.f;
#pragma unroll
    for (int mt = 0; mt < 4; ++mt)
#pragma unroll
        for (int reg = 0; reg < 4; ++reg) {
            int r = row0 + wm + mt * 16 + quad * 4 + reg;
#pragma unroll
            for (int nt = 0; nt < 4; ++nt) {
                int c = col0 + wn + nt * 16 + col;
                float v = acc[mt][nt][reg] + bv4[nt];
                if (OUT_BF16) ((short*)Cv)[(size_t)r * N + c] = f2bf(v);
                else          ((float*)Cv)[(size_t)r * N + c] = v;
            }
        }
}

// QKV (768 tiles, XCD-swizzled) + pos (64 tiles) in one dispatch
__global__ __launch_bounds__(256) void gemm_qkv_pos(
    const short* __restrict__ xb, const short* __restrict__ wqkv,
    const float* __restrict__ bqkv, short* __restrict__ QKV,
    const short* __restrict__ posb, const short* __restrict__ wpb,
    short* __restrict__ Pm)
{
    __shared__ short As[8192], Bs[8192];
    const int bid = blockIdx.x;
    if (bid < 768) {
        const int xcd = bid & 7, s = bid >> 3;
        const int row = xcd * 8 + (s & 7), colt = s >> 3;   // row 0..63, colt 0..11
        gemm_tile<1>(As, Bs, xb, wqkv, bqkv, QKV, 1536, 512, row * 128, colt * 128);
    } else {
        const int t = bid - 768;
        gemm_tile<1>(As, Bs, posb, wpb, nullptr, Pm, 512, 512, (t / 4) * 128, (t % 4) * 128);
    }
}

__global__ __launch_bounds__(256) void gemm_out_kernel(
    const short* __restrict__ A, const short* __restrict__ B,
    const float* __restrict__ bias, float* __restrict__ C)
{
    __shared__ short As[8192], Bs[8192];
    const int bid = blockIdx.x;
    const int xcd = bid & 7, s = bid >> 3;
    const int row = xcd * 8 + (s & 7), colt = s >> 3;       // row 0..63, colt 0..3
    gemm_tile<0>(As, Bs, A, B, bias, C, 512, 512, row * 128, colt * 128);
}

// ---------------- fused: KP = K+P, cb = (log2e/8)*(u.k+vb.p), Vt transpose -----
__global__ __launch_bounds__(256) void kvprep_kernel(
    const short* __restrict__ qkv, const short* __restrict__ pm,
    const float* __restrict__ u, const float* __restrict__ vb,
    short* __restrict__ kp, short* __restrict__ vt, float* __restrict__ cb)
{
    __shared__ short tile[64][72];
    const int tid = threadIdx.x, lr = tid >> 2, lc = (tid & 3) * 16;
    const int bh = blockIdx.y, b = bh >> 3, h = bh & 7, s0 = blockIdx.x * 64;

    const short* kptr = qkv + (size_t)(b * T_SEQ + s0 + lr) * 1536 + 512 + h * DK + lc;
    const short* pptr = pm + (size_t)(s0 + lr) * NFEAT + h * DK + lc;
    const short* vptr = qkv + (size_t)(b * T_SEQ + s0 + lr) * 1536 + 1024 + h * DK + lc;
    bf16x8 k0_ = *(const bf16x8*)kptr,       k1_ = *(const bf16x8*)(kptr + 8);
    bf16x8 p0_ = *(const bf16x8*)pptr,       p1_ = *(const bf16x8*)(pptr + 8);
    bf16x8 v0_ = *(const bf16x8*)vptr,       v1_ = *(const bf16x8*)(vptr + 8);

    float c = 0.f;
    bf16x8 o0, o1;
#pragma unroll
    for (int j = 0; j < 8; ++j) {
        float kf = b2f(k0_[j]), pf = b2f(p0_[j]);
        o0[j] = f2bf(kf + pf);
        c += u[h * DK + lc + j] * kf + vb[h * DK + lc + j] * pf;
        float kf1 = b2f(k1_[j]), pf1 = b2f(p1_[j]);
        o1[j] = f2bf(kf1 + pf1);
        c += u[h * DK + lc + 8 + j] * kf1 + vb[h * DK + lc + 8 + j] * pf1;
    }
    short* kpd = kp + ((size_t)bh * T_SEQ + s0 + lr) * DK + lc;
    *(bf16x8*)kpd       = o0;
    *(bf16x8*)(kpd + 8) = o1;
    c += __shfl_xor(c, 1);
    c += __shfl_xor(c, 2);
    if ((tid & 3) == 0) cb[(size_t)bh * T_SEQ + s0 + lr] = LOG2E_8 * c;

    *(bf16x8*)&tile[lr][lc]     = v0_;
    *(bf16x8*)&tile[lr][lc + 8] = v1_;
    __syncthreads();
    short* dst = vt + (size_t)(bh * DK + lr) * T_SEQ + s0 + lc;
    bf16x8 t0_, t1_;
#pragma unroll
    for (int j = 0; j < 8; ++j) { t0_[j] = tile[lc + j][lr]; t1_[j] = tile[lc + 8 + j][lr]; }
    *(bf16x8*)dst       = t0_;
    *(bf16x8*)(dst + 8) = t1_;
}

// ---------------- flash attention, key-split 2-way -----------------------------
// Grid 1024 (4 blocks/CU): block = (bh, t-tile of 128, key-half of 1024).
// 4 waves x 32 Q-rows; unnormalized bf16 partial O + per-row l written out;
// combine_kernel merges halves. XCD pinning preserved (4 bh per XCD).
__global__ __launch_bounds__(256, 4) void attn_kernel(
    const short* __restrict__ qkv, const short* __restrict__ kp,
    const short* __restrict__ vt, const float* __restrict__ cb,
    short* __restrict__ Op, float* __restrict__ Lb)
{
    __shared__ __align__(16) short KPs[64][72], Vts[64][72], Ps[4][32][72];
    __shared__ float cs[64];
    const int tid = threadIdx.x, lane = tid & 63, wave = tid >> 6;   // 4 waves
    const int col = lane & 15, quad = lane >> 4;
    const int idx = blockIdx.x;
    const int xcd = idx & 7, slot = idx >> 3;        // slot 0..127
    const int half = slot & 1;
    const int t0 = ((slot >> 1) & 15) * 128;
    const int bh = (slot >> 5) * 8 + xcd;            // 4 bh per XCD -> 2MB KV in L2
    const int base = half * 1024;                    // key range [base, base+1024)
    const int b = bh >> 3, h = bh & 7;

    // Q fragments straight from global: rows t0 + wave*32 + g*16 + col
    bf16x8 qa[2][2];
#pragma unroll
    for (int g = 0; g < 2; ++g) {
        const short* qb = qkv + (size_t)(b * T_SEQ + t0 + wave * 32 + g * 16 + col) * 1536 + h * DK + quad * 8;
        qa[g][0] = *(const bf16x8*)qb;
        qa[g][1] = *(const bf16x8*)(qb + 32);
    }

    const int lr  = tid >> 2;             // 0..63 staging row
    const int lcq = (tid & 3) * 16;       // 0,16,32,48
    const int rho = 4 * (lr & 15) + (lr >> 4);   // key permutation for KP rows

    const short* kpbase = kp + (size_t)bh * T_SEQ * DK;
    const short* vtbase = vt + (size_t)bh * DK * T_SEQ;

    // prime the register pipeline (first tile of this half)
    bf16x8 kpr0 = *(const bf16x8*)(kpbase + (size_t)(base + rho) * DK + lcq);
    bf16x8 kpr1 = *(const bf16x8*)(kpbase + (size_t)(base + rho) * DK + lcq + 8);
    bf16x8 vtr0 = *(const bf16x8*)(vtbase + (size_t)lr * T_SEQ + base + lcq);
    bf16x8 vtr1 = *(const bf16x8*)(vtbase + (size_t)lr * T_SEQ + base + lcq + 8);
    float cbr = (tid < 64) ? cb[(size_t)bh * T_SEQ + base + tid] : 0.f;

    f32x4 Oacc[2][4];
    float lsum[2][4];
#pragma unroll
    for (int g = 0; g < 2; ++g)
#pragma unroll
        for (int i = 0; i < 4; ++i) { Oacc[g][i] = (f32x4){0.f, 0.f, 0.f, 0.f}; lsum[g][i] = 0.f; }

    for (int it = 0; it < 16; ++it) {
        __syncthreads();                 // prev iter's KPs/Vts reads done
        *(bf16x8*)&KPs[lr][lcq]     = kpr0;
        *(bf16x8*)&KPs[lr][lcq + 8] = kpr1;
        *(bf16x8*)&Vts[lr][lcq]     = vtr0;
        *(bf16x8*)&Vts[lr][lcq + 8] = vtr1;
        if (tid < 64) cs[tid] = cbr;
        __syncthreads();

        // prefetch next tile (wraps within this half on last iter)
        const int sn = base + (((it + 1) & 15) << 6);
        kpr0 = *(const bf16x8*)(kpbase + (size_t)(sn + rho) * DK + lcq);
        kpr1 = *(const bf16x8*)(kpbase + (size_t)(sn + rho) * DK + lcq + 8);
        vtr0 = *(const bf16x8*)(vtbase + (size_t)lr * T_SEQ + sn + lcq);
        vtr1 = *(const bf16x8*)(vtbase + (size_t)lr * T_SEQ + sn + lcq + 8);
        if (tid < 64) cbr = cb[(size_t)bh * T_SEQ + sn + tid];

        // QK: B-fragments read ONCE, used by both row-groups
        f32x4 S[2][4];
#pragma unroll
        for (int g = 0; g < 2; ++g)
#pragma unroll
            for (int nt = 0; nt < 4; ++nt) S[g][nt] = (f32x4){0.f, 0.f, 0.f, 0.f};
#pragma unroll
        for (int nt = 0; nt < 4; ++nt) {
            bf16x8 b0 = *(const bf16x8*)&KPs[nt * 16 + col][quad * 8];
            bf16x8 b1 = *(const bf16x8*)&KPs[nt * 16 + col][32 + quad * 8];
            S[0][nt] = __builtin_amdgcn_mfma_f32_16x16x32_bf16(qa[0][0], b0, S[0][nt], 0, 0, 0);
            S[1][nt] = __builtin_amdgcn_mfma_f32_16x16x32_bf16(qa[1][0], b0, S[1][nt], 0, 0, 0);
            S[0][nt] = __builtin_amdgcn_mfma_f32_16x16x32_bf16(qa[0][1], b1, S[0][nt], 0, 0, 0);
            S[1][nt] = __builtin_amdgcn_mfma_f32_16x16x32_bf16(qa[1][1], b1, S[1][nt], 0, 0, 0);
        }
        // lane's score (nt,reg) = key 4*col+nt (via rho) -> packed b64 writes
        const f4 cv = *(const f4*)&cs[4 * col];
#pragma unroll
        for (int g = 0; g < 2; ++g)
#pragma unroll
            for (int reg = 0; reg < 4; ++reg) {
                float e0 = __builtin_amdgcn_exp2f(fmaf(S[g][0][reg], LOG2E_8, cv[0]));
                float e1 = __builtin_amdgcn_exp2f(fmaf(S[g][1][reg], LOG2E_8, cv[1]));
                float e2 = __builtin_amdgcn_exp2f(fmaf(S[g][2][reg], LOG2E_8, cv[2]));
                float e3 = __builtin_amdgcn_exp2f(fmaf(S[g][3][reg], LOG2E_8, cv[3]));
                lsum[g][reg] += (e0 + e1) + (e2 + e3);
                i32x2 pw; pw[0] = pkbf(e0, e1); pw[1] = pkbf(e2, e3);
                *(i32x2*)&Ps[wave][g * 16 + quad * 4 + reg][4 * col] = pw;
            }
        // PV: Vt fragments read ONCE, used by both row-groups (no barrier: per-wave Ps)
#pragma unroll
        for (int kt = 0; kt < 2; ++kt) {
            bf16x8 pa0 = *(const bf16x8*)&Ps[wave][col][kt * 32 + quad * 8];
            bf16x8 pa1 = *(const bf16x8*)&Ps[wave][16 + col][kt * 32 + quad * 8];
#pragma unroll
            for (int dt = 0; dt < 4; ++dt) {
                bf16x8 vb = *(const bf16x8*)&Vts[dt * 16 + col][kt * 32 + quad * 8];
                Oacc[0][dt] = __builtin_amdgcn_mfma_f32_16x16x32_bf16(pa0, vb, Oacc[0][dt], 0, 0, 0);
                Oacc[1][dt] = __builtin_amdgcn_mfma_f32_16x16x32_bf16(pa1, vb, Oacc[1][dt], 0, 0, 0);
            }
        }
    }
    // epilogue: write UNNORMALIZED partial O (bf16) + per-row l
    short* ophalf = Op + (size_t)half * 4194304;
    float* lhalf  = Lb + (size_t)half * 65536 + (size_t)bh * T_SEQ;
#pragma unroll
    for (int g = 0; g < 2; ++g)
#pragma unroll
        for (int reg = 0; reg < 4; ++reg) {
            float l = lsum[g][reg];
#pragma unroll
            for (int off = 1; off < 16; off <<= 1) l += __shfl_xor(l, off);
            int t = t0 + wave * 32 + g * 16 + quad * 4 + reg;
            if (col == 0) lhalf[t] = l;
            short* op = ophalf + (size_t)(b * T_SEQ + t) * NFEAT + h * DK;
#pragma unroll
            for (int dt = 0; dt < 4; ++dt)
                op[dt * 16 + col] = f2bf(Oacc[g][dt][reg]);
        }
}

// ---------------- combine: AttO = (O1+O2)/(l1+l2) ------------------------------
__global__ __launch_bounds__(256) void combine_kernel(
    const short* __restrict__ Op, const float* __restrict__ Lb,
    short* __restrict__ attO)
{
    const int e = blockIdx.x * 256 + threadIdx.x;   // 0..524287, 8 elems each
    const int flat = e * 8;
    const int r = flat >> 9, c = flat & 511;
    const int bh = ((r >> 11) << 3) + (c >> 6);
    const int t = r & 2047;
    const float l = Lb[bh * T_SEQ + t] + Lb[65536 + bh * T_SEQ + t];
    const float inv = 1.f / l;
    bf16x8 o1 = *(const bf16x8*)(Op + flat);
    bf16x8 o2 = *(const bf16x8*)(Op + 4194304 + flat);
    bf16x8 o;
#pragma unroll
    for (int j = 0; j < 8; ++j) o[j] = f2bf((b2f(o1[j]) + b2f(o2[j])) * inv);
    *(bf16x8*)(attO + flat) = o;
}

extern "C" void kernel_launch(void* const* d_in, const int* in_sizes, int n_in,
                              void* d_out, int out_size, void* d_ws, size_t ws_size,
                              hipStream_t stream)
{
    const float* x    = (const float*)d_in[0];
    const float* pos  = (const float*)d_in[1];
    const float* Wq   = (const float*)d_in[2];
    const float* bq   = (const float*)d_in[3];
    const float* Wk   = (const float*)d_in[4];
    const float* bk   = (const float*)d_in[5];
    const float* Wv   = (const float*)d_in[6];
    const float* bv   = (const float*)d_in[7];
    const float* Wpos = (const float*)d_in[8];
    const float* Wout = (const float*)d_in[9];
    const float* bout = (const float*)d_in[10];
    const float* pbu  = (const float*)d_in[11];
    const float* pbv  = (const float*)d_in[12];
    float* out = (float*)d_out;

    short* xb   = (short*)d_ws;            // 4,194,304
    short* posb = xb   + 4194304;          // 1,048,576
    short* wqkv = posb + 1048576;          //   786,432
    short* wpb  = wqkv + 786432;           //   262,144
    short* wob  = wpb  + 262144;           //   262,144
    short* QKV  = wob  + 262144;           // 12,582,912  [8192][1536] (Q|K|V)
    short* Pm   = QKV  + 12582912;         // 1,048,576   [2048][512]
    short* KP   = Pm   + 1048576;          // 4,194,304   [bh][s][64]
    short* Vt   = KP   + 4194304;          // 4,194,304   [bh][d][t]
    short* AttO = Vt   + 4194304;          // 4,194,304   [8192][512]
    float* bqkv = (float*)(AttO + 4194304);
    float* Cb   = bqkv + 1536;             // 65,536
    short* Op   = (short*)(Cb + 65536);    // 8,388,608 shorts (two bf16 partials)
    float* Lb   = (float*)(Op + 8388608);  // 131,072 floats (two l partials)

    cvt_kernel<<<dim3(3201), dim3(256), 0, stream>>>(x, pos, Wq, Wk, Wv, Wpos, Wout, bq, bk, bv,
                                                     xb, posb, wqkv, wpb, wob, bqkv);
    gemm_qkv_pos<<<dim3(832), dim3(256), 0, stream>>>(xb, wqkv, bqkv, QKV, posb, wpb, Pm);
    kvprep_kernel<<<dim3(T_SEQ / 64, BATCH * NHEAD), dim3(256), 0, stream>>>(QKV, Pm, pbu, pbv, KP, Vt, Cb);
    attn_kernel<<<dim3(1024), dim3(256), 0, stream>>>(QKV, KP, Vt, Cb, Op, Lb);
    combine_kernel<<<dim3(2048), dim3(256), 0, stream>>>(Op, Lb, AttO);
    gemm_out_kernel<<<dim3(256), dim3(256), 0, stream>>>(AttO, wob, bout, out);
}